// Round 7
// baseline (759.007 us; speedup 1.0000x reference)
//
#include <hip/hip_runtime.h>
#include <cstdint>
#include <cstddef>

#define NF 128
#define NH 64

typedef unsigned int uint32;

// bf16 helpers (RNE pack, cheap unpack)
__device__ inline unsigned short f2bf(float f) {
  unsigned int u = __float_as_uint(f);
  return (unsigned short)((u + 0x7FFF + ((u >> 16) & 1)) >> 16);
}
__device__ inline float bf2f_lo(uint32 u) { return __uint_as_float(u << 16); }
__device__ inline float bf2f_hi(uint32 u) { return __uint_as_float(u & 0xFFFF0000u); }

// ---------------- build kernels ----------------

// dst-windowed count: pass = blockIdx%8 -> one XCD per window (L2-local atomics)
__global__ __launch_bounds__(256) void count_kernel(const int* __restrict__ ei, int E,
                                                    int* __restrict__ cnt, int RW) {
  int pass = blockIdx.x & 7;
  int i = (blockIdx.x >> 3) * 256 + threadIdx.x;
  if (i * 4 >= E) return;
  int4 d = ((const int4*)(ei + E))[i];
  int lo = pass * RW, hi = lo + RW;
  if (d.x >= lo && d.x < hi) atomicAdd(&cnt[d.x], 1);
  if (d.y >= lo && d.y < hi) atomicAdd(&cnt[d.y], 1);
  if (d.z >= lo && d.z < hi) atomicAdd(&cnt[d.z], 1);
  if (d.w >= lo && d.w < hi) atomicAdd(&cnt[d.w], 1);
}

// per-1024-element block sums
__global__ __launch_bounds__(256) void partial_kernel(const int* __restrict__ cnt, int N,
                                                      int* __restrict__ part) {
  __shared__ int sd[256];
  int t = threadIdx.x;
  int idx = blockIdx.x * 1024 + t * 4;
  int s = 0;
#pragma unroll
  for (int j = 0; j < 4; ++j)
    if (idx + j < N) s += cnt[idx + j];
  sd[t] = s;
  __syncthreads();
  for (int off = 128; off > 0; off >>= 1) {
    if (t < off) sd[t] += sd[t + off];
    __syncthreads();
  }
  if (t == 0) part[blockIdx.x] = sd[0];
}

// exclusive-scan the block partials (NB <= 128), write total to rowptr[N]
__global__ __launch_bounds__(128) void scanp_kernel(int* __restrict__ part, int NB,
                                                    int* __restrict__ rowptrN) {
  __shared__ int s[128];
  int t = threadIdx.x;
  int v = (t < NB) ? part[t] : 0;
  s[t] = v;
  __syncthreads();
  for (int off = 1; off < 128; off <<= 1) {
    int add = (t >= off) ? s[t - off] : 0;
    __syncthreads();
    s[t] += add;
    __syncthreads();
  }
  if (t < NB) part[t] = s[t] - v;  // exclusive
  if (t == 0) rowptrN[0] = s[127];
}

// rowptr (exclusive scan of cnt) + cnt2 (running cursor copy) + dinv
__global__ __launch_bounds__(256) void rowptr_kernel(const int* __restrict__ cnt,
                                                     const int* __restrict__ part,
                                                     int* __restrict__ rowptr,
                                                     int* __restrict__ cnt2,
                                                     float* __restrict__ dinv, int N) {
  __shared__ int s[256];
  int t = threadIdx.x;
  int idx = blockIdx.x * 1024 + t * 4;
  int c[4];
  int ts = 0;
#pragma unroll
  for (int j = 0; j < 4; ++j) {
    c[j] = (idx + j < N) ? cnt[idx + j] : 0;
    ts += c[j];
  }
  s[t] = ts;
  __syncthreads();
  for (int off = 1; off < 256; off <<= 1) {
    int add = (t >= off) ? s[t - off] : 0;
    __syncthreads();
    s[t] += add;
    __syncthreads();
  }
  int run = s[t] - ts + part[blockIdx.x];
#pragma unroll
  for (int j = 0; j < 4; ++j) {
    if (idx + j < N) {
      rowptr[idx + j] = run;
      cnt2[idx + j] = run;
      dinv[idx + j] = rsqrtf((float)(c[j] + 1));
    }
    run += c[j];
  }
}

// dst-windowed CSR scatter (src, weight), pass = blockIdx%8 -> one XCD per
// col2 window so lines assemble in that XCD's L2 before writeback.
__global__ __launch_bounds__(256) void fill_kernel(const int* __restrict__ ei, int E,
                                                   int* __restrict__ cnt2,
                                                   const float* __restrict__ dinv,
                                                   int2* __restrict__ col2, int RW) {
  int pass = blockIdx.x & 7;
  int i = (blockIdx.x >> 3) * 256 + threadIdx.x;
  if (i * 4 >= E) return;
  int4 sv = ((const int4*)ei)[i];
  int4 dv = ((const int4*)(ei + E))[i];
  int lo = pass * RW, hi = lo + RW;
  int ss[4] = {sv.x, sv.y, sv.z, sv.w};
  int dd[4] = {dv.x, dv.y, dv.z, dv.w};
#pragma unroll
  for (int j = 0; j < 4; ++j) {
    int d = dd[j];
    if (d < lo || d >= hi) continue;
    int s = ss[j];
    float w = dinv[s] * dinv[d];
    int pos = atomicAdd(&cnt2[d], 1);
    col2[pos] = make_int2(s, __float_as_int(w));
  }
}

// ---------------- compute kernels ----------------

// Hs layout: 8 slices; slice j = uint32[N*4]; row n = 4 uint32 = 8 bf16 feats
// (features j*8 .. j*8+7). Slice = 1.6 MB -> resident in one XCD's 4 MB L2.

// gemm1: Hs[n] = x[n] @ W1 (f32 in, sliced bf16 out). Block = 64 nodes.
template <int K>
__global__ __launch_bounds__(256, 4) void gemm_kernel(const float* __restrict__ X,
                                                      const float* __restrict__ W,
                                                      uint32* __restrict__ Hs, int N) {
  __shared__ float XsT[64][68];
  __shared__ float Ws[64 * 64];
  const int tid = threadIdx.x;
  const int n0 = blockIdx.x * 64;
  const int tn = (tid >> 4) * 4;
  const int tf = (tid & 15) * 4;

  float acc[4][4];
#pragma unroll
  for (int i = 0; i < 4; ++i)
#pragma unroll
    for (int j = 0; j < 4; ++j) acc[i][j] = 0.f;

  for (int kt = 0; kt < K / 64; ++kt) {
    {
      const float4* Wg = (const float4*)(W + (size_t)kt * 64 * 64);
      float4* Wl = (float4*)Ws;
#pragma unroll
      for (int j = 0; j < 4; ++j) Wl[tid + j * 256] = Wg[tid + j * 256];
    }
#pragma unroll
    for (int j = 0; j < 4; ++j) {
      int idx = tid + j * 256;
      int n = idx >> 4;
      int kq = idx & 15;
      float4 v = make_float4(0.f, 0.f, 0.f, 0.f);
      if (n0 + n < N)
        v = *(const float4*)(X + (size_t)(n0 + n) * K + kt * 64 + kq * 4);
      XsT[kq * 4 + 0][n] = v.x;
      XsT[kq * 4 + 1][n] = v.y;
      XsT[kq * 4 + 2][n] = v.z;
      XsT[kq * 4 + 3][n] = v.w;
    }
    __syncthreads();
#pragma unroll 8
    for (int k = 0; k < 64; ++k) {
      float4 xv = *(const float4*)(&XsT[k][tn]);
      float4 wv = *(const float4*)(&Ws[k * 64 + tf]);
      acc[0][0] = fmaf(xv.x, wv.x, acc[0][0]);
      acc[0][1] = fmaf(xv.x, wv.y, acc[0][1]);
      acc[0][2] = fmaf(xv.x, wv.z, acc[0][2]);
      acc[0][3] = fmaf(xv.x, wv.w, acc[0][3]);
      acc[1][0] = fmaf(xv.y, wv.x, acc[1][0]);
      acc[1][1] = fmaf(xv.y, wv.y, acc[1][1]);
      acc[1][2] = fmaf(xv.y, wv.z, acc[1][2]);
      acc[1][3] = fmaf(xv.y, wv.w, acc[1][3]);
      acc[2][0] = fmaf(xv.z, wv.x, acc[2][0]);
      acc[2][1] = fmaf(xv.z, wv.y, acc[2][1]);
      acc[2][2] = fmaf(xv.z, wv.z, acc[2][2]);
      acc[2][3] = fmaf(xv.z, wv.w, acc[2][3]);
      acc[3][0] = fmaf(xv.w, wv.x, acc[3][0]);
      acc[3][1] = fmaf(xv.w, wv.y, acc[3][1]);
      acc[3][2] = fmaf(xv.w, wv.z, acc[3][2]);
      acc[3][3] = fmaf(xv.w, wv.w, acc[3][3]);
    }
    __syncthreads();
  }
  const int jj = tf >> 3;        // slice
  const int q0 = (tf & 7) >> 1;  // uint32 offset within row (0 or 2)
#pragma unroll
  for (int i = 0; i < 4; ++i) {
    int n = n0 + tn + i;
    if (n < N) {
      uint32 a = (uint32)f2bf(acc[i][0]) | ((uint32)f2bf(acc[i][1]) << 16);
      uint32 b = (uint32)f2bf(acc[i][2]) | ((uint32)f2bf(acc[i][3]) << 16);
      *(uint2*)(Hs + (size_t)jj * N * 4 + (size_t)n * 4 + q0) = make_uint2(a, b);
    }
  }
}

// Aggregation over one feature slice. Block pinned to XCD = blockIdx&7 ->
// slice j resident in that XCD's L2; gathers are random 16B L2 HITS.
// Wave = 4 nodes x 4 edges x 4 lanes. Edge stream read nontemporal so it
// doesn't evict the slice. r = relu(sum + bias) written sliced bf16 to Rs.
__global__ __launch_bounds__(256) void agg_kernel(
    const uint32* __restrict__ Hs, const int* __restrict__ rowptr,
    const int2* __restrict__ col2, const float* __restrict__ dinv,
    const float* __restrict__ bias, uint32* __restrict__ Rs, int N) {
  const int slice = blockIdx.x & 7;
  const int lane = threadIdx.x & 63;
  const int wv = threadIdx.x >> 6;
  const int g = lane >> 4;          // node sub-group 0..3
  const int sub = (lane >> 2) & 3;  // edge slot within batch
  const int q = lane & 3;           // uint32 index within 16B slice row

  int n = (blockIdx.x >> 3) * 16 + wv * 4 + g;
  const bool nvalid = n < N;
  const int ns = nvalid ? n : N - 1;
  const int e0 = rowptr[ns];
  const int m = nvalid ? (rowptr[ns + 1] - e0) : 0;
  const uint32* Hj = Hs + (size_t)slice * N * 4;

  float acc0 = 0.f, acc1 = 0.f;
  int itmax = (m + 3) >> 2;
  itmax = max(itmax, __shfl_xor(itmax, 16, 64));
  itmax = max(itmax, __shfl_xor(itmax, 32, 64));
  for (int it = 0; it < itmax; ++it) {
    int er = it * 4 + sub;
    bool v = er < m;
    int e = v ? (e0 + er) : 0;
    unsigned long long c =
        __builtin_nontemporal_load((const unsigned long long*)col2 + e);
    int src = (int)(c & 0xFFFFFFFFull);
    float w = v ? __uint_as_float((uint32)(c >> 32)) : 0.f;
    uint32 u = Hj[(size_t)src * 4 + q];
    acc0 = fmaf(w, bf2f_lo(u), acc0);
    acc1 = fmaf(w, bf2f_hi(u), acc1);
  }
  // sum the 4 edge slots within each 16-lane node group
  acc0 += __shfl_xor(acc0, 4, 64);
  acc0 += __shfl_xor(acc0, 8, 64);
  acc1 += __shfl_xor(acc1, 4, 64);
  acc1 += __shfl_xor(acc1, 8, 64);
  // self loop
  float di = dinv[ns];
  float d2 = di * di;
  uint32 su = Hj[(size_t)ns * 4 + q];
  acc0 = fmaf(d2, bf2f_lo(su), acc0);
  acc1 = fmaf(d2, bf2f_hi(su), acc1);

  float2 bv = ((const float2*)bias)[slice * 4 + q];
  float r0 = acc0 + bv.x;
  float r1 = acc1 + bv.y;
  r0 = r0 > 0.f ? r0 : 0.f;
  r1 = r1 > 0.f ? r1 : 0.f;
  if (nvalid && sub == 0) {
    uint32 p = (uint32)f2bf(r0) | ((uint32)f2bf(r1) << 16);
    __builtin_nontemporal_store(p, Rs + (size_t)slice * N * 4 + (size_t)n * 4 + q);
  }
}

// transform: Hs_next = Rs @ W (64x64). Sliced bf16 in, sliced bf16 out.
__global__ __launch_bounds__(256, 4) void transform_kernel(
    const uint32* __restrict__ Rs, const float* __restrict__ W,
    uint32* __restrict__ Hs, int N) {
  __shared__ float XsT[64][68];
  __shared__ float Ws[64 * 64];
  const int tid = threadIdx.x;
  const int n0 = blockIdx.x * 64;
  const int tn = (tid >> 4) * 4;
  const int tf = (tid & 15) * 4;
  {
    const float4* Wg = (const float4*)W;
    float4* Wl = (float4*)Ws;
#pragma unroll
    for (int j = 0; j < 4; ++j) Wl[tid + j * 256] = Wg[tid + j * 256];
  }
#pragma unroll
  for (int it = 0; it < 2; ++it) {
    int sb = it * 256 + tid;  // 0..511
    int n = sb & 63;
    int j = sb >> 6;  // slice
    uint4 v = make_uint4(0, 0, 0, 0);
    if (n0 + n < N)
      v = *(const uint4*)(Rs + (size_t)j * N * 4 + (size_t)(n0 + n) * 4);
    XsT[j * 8 + 0][n] = bf2f_lo(v.x);
    XsT[j * 8 + 1][n] = bf2f_hi(v.x);
    XsT[j * 8 + 2][n] = bf2f_lo(v.y);
    XsT[j * 8 + 3][n] = bf2f_hi(v.y);
    XsT[j * 8 + 4][n] = bf2f_lo(v.z);
    XsT[j * 8 + 5][n] = bf2f_hi(v.z);
    XsT[j * 8 + 6][n] = bf2f_lo(v.w);
    XsT[j * 8 + 7][n] = bf2f_hi(v.w);
  }
  __syncthreads();
  float acc[4][4];
#pragma unroll
  for (int i = 0; i < 4; ++i)
#pragma unroll
    for (int j = 0; j < 4; ++j) acc[i][j] = 0.f;
#pragma unroll 8
  for (int k = 0; k < 64; ++k) {
    float4 xv = *(const float4*)(&XsT[k][tn]);
    float4 wv = *(const float4*)(&Ws[k * 64 + tf]);
    acc[0][0] = fmaf(xv.x, wv.x, acc[0][0]);
    acc[0][1] = fmaf(xv.x, wv.y, acc[0][1]);
    acc[0][2] = fmaf(xv.x, wv.z, acc[0][2]);
    acc[0][3] = fmaf(xv.x, wv.w, acc[0][3]);
    acc[1][0] = fmaf(xv.y, wv.x, acc[1][0]);
    acc[1][1] = fmaf(xv.y, wv.y, acc[1][1]);
    acc[1][2] = fmaf(xv.y, wv.z, acc[1][2]);
    acc[1][3] = fmaf(xv.y, wv.w, acc[1][3]);
    acc[2][0] = fmaf(xv.z, wv.x, acc[2][0]);
    acc[2][1] = fmaf(xv.z, wv.y, acc[2][1]);
    acc[2][2] = fmaf(xv.z, wv.z, acc[2][2]);
    acc[2][3] = fmaf(xv.z, wv.w, acc[2][3]);
    acc[3][0] = fmaf(xv.w, wv.x, acc[3][0]);
    acc[3][1] = fmaf(xv.w, wv.y, acc[3][1]);
    acc[3][2] = fmaf(xv.w, wv.z, acc[3][2]);
    acc[3][3] = fmaf(xv.w, wv.w, acc[3][3]);
  }
  const int jj = tf >> 3;
  const int q0 = (tf & 7) >> 1;
#pragma unroll
  for (int i = 0; i < 4; ++i) {
    int n = n0 + tn + i;
    if (n < N) {
      uint32 a = (uint32)f2bf(acc[i][0]) | ((uint32)f2bf(acc[i][1]) << 16);
      uint32 b = (uint32)f2bf(acc[i][2]) | ((uint32)f2bf(acc[i][3]) << 16);
      *(uint2*)(Hs + (size_t)jj * N * 4 + (size_t)n * 4 + q0) = make_uint2(a, b);
    }
  }
}

// final: logits = Rs3 @ Wlin + blin -> log_softmax. Wave per node.
__global__ __launch_bounds__(256) void final_kernel(
    const uint32* __restrict__ Rs, const float* __restrict__ Wlin,
    const float* __restrict__ blin, float* __restrict__ out, int N) {
  int lane = threadIdx.x & 63;
  int n = blockIdx.x * 4 + (threadIdx.x >> 6);
  if (n >= N) return;
  float t0 = 0.f, t1 = 0.f;
  if (lane < 32) {
    int j = lane >> 2, q = lane & 3;
    uint32 u = Rs[(size_t)j * N * 4 + (size_t)n * 4 + q];
    float r0 = bf2f_lo(u), r1 = bf2f_hi(u);
    int f0 = j * 8 + q * 2;
    float4 wl = *(const float4*)(Wlin + f0 * 2);
    t0 = r0 * wl.x + r1 * wl.z;
    t1 = r0 * wl.y + r1 * wl.w;
  }
#pragma unroll
  for (int off = 32; off > 0; off >>= 1) {
    t0 += __shfl_xor(t0, off, 64);
    t1 += __shfl_xor(t1, off, 64);
  }
  if (lane == 0) {
    float l0 = t0 + blin[0];
    float l1 = t1 + blin[1];
    float mx = fmaxf(l0, l1);
    float lz = mx + logf(expf(l0 - mx) + expf(l1 - mx));
    out[(size_t)n * 2 + 0] = l0 - lz;
    out[(size_t)n * 2 + 1] = l1 - lz;
  }
}

// ---------------- launcher ----------------

extern "C" void kernel_launch(void* const* d_in, const int* in_sizes, int n_in,
                              void* d_out, int out_size, void* d_ws, size_t ws_size,
                              hipStream_t stream) {
  const float* x  = (const float*)d_in[0];
  const int*   ei = (const int*)d_in[1];
  const float* W1 = (const float*)d_in[2];
  const float* b1 = (const float*)d_in[3];
  const float* W2 = (const float*)d_in[4];
  const float* b2 = (const float*)d_in[5];
  const float* W3 = (const float*)d_in[6];
  const float* b3 = (const float*)d_in[7];
  const float* Wl = (const float*)d_in[8];
  const float* bl = (const float*)d_in[9];
  float* out = (float*)d_out;

  const int N = in_sizes[0] / NF;  // 100000
  const int E = in_sizes[1] / 2;   // 1600000

  char* w = (char*)d_ws;
  size_t off = 0;
  auto alloc = [&](size_t bytes) {
    void* p = w + off;
    off += bytes;
    off = (off + 15) & ~(size_t)15;
    return p;
  };
  int*    cnt    = (int*)alloc((size_t)N * 4);
  int*    cnt2   = (int*)alloc((size_t)N * 4);
  int*    rowptr = (int*)alloc((size_t)(N + 1) * 4);
  int*    part   = (int*)alloc(256 * 4);
  float*  dinv   = (float*)alloc((size_t)N * 4);
  int2*   col2   = (int2*)alloc((size_t)E * 8);
  uint32* Hbuf   = (uint32*)alloc((size_t)N * 32 * 4);  // 8 slices x N x 4 u32
  uint32* Rbuf   = (uint32*)alloc((size_t)N * 32 * 4);

  const int NB = (N + 1023) / 1024;       // 98 (<=128 required by scanp)
  const int RW = (N + 7) / 8;             // 12500-node dst window per XCD
  const int NCHUNK = (E / 4 + 255) / 256; // edge-quad chunks
  const int AGGB = 8 * ((N + 15) / 16);   // 8 slices x 16-node blocks

  hipMemsetAsync(cnt, 0, (size_t)N * 4, stream);
  hipLaunchKernelGGL(count_kernel, dim3(8 * NCHUNK), dim3(256), 0, stream,
                     ei, E, cnt, RW);
  hipLaunchKernelGGL(partial_kernel, dim3(NB), dim3(256), 0, stream, cnt, N, part);
  hipLaunchKernelGGL(scanp_kernel, dim3(1), dim3(128), 0, stream, part, NB, rowptr + N);
  hipLaunchKernelGGL(rowptr_kernel, dim3(NB), dim3(256), 0, stream,
                     cnt, part, rowptr, cnt2, dinv, N);
  hipLaunchKernelGGL(fill_kernel, dim3(8 * NCHUNK), dim3(256), 0, stream,
                     ei, E, cnt2, dinv, col2, RW);

  hipLaunchKernelGGL(gemm_kernel<128>, dim3((N + 63) / 64), dim3(256), 0, stream,
                     x, W1, Hbuf, N);
  hipLaunchKernelGGL(agg_kernel, dim3(AGGB), dim3(256), 0, stream,
                     Hbuf, rowptr, col2, dinv, b1, Rbuf, N);
  hipLaunchKernelGGL(transform_kernel, dim3((N + 63) / 64), dim3(256), 0, stream,
                     Rbuf, W2, Hbuf, N);
  hipLaunchKernelGGL(agg_kernel, dim3(AGGB), dim3(256), 0, stream,
                     Hbuf, rowptr, col2, dinv, b2, Rbuf, N);
  hipLaunchKernelGGL(transform_kernel, dim3((N + 63) / 64), dim3(256), 0, stream,
                     Rbuf, W3, Hbuf, N);
  hipLaunchKernelGGL(agg_kernel, dim3(AGGB), dim3(256), 0, stream,
                     Hbuf, rowptr, col2, dinv, b3, Rbuf, N);
  hipLaunchKernelGGL(final_kernel, dim3((N + 3) / 4), dim3(256), 0, stream,
                     Rbuf, Wl, bl, out, N);
}

// Round 9
// 476.409 us; speedup vs baseline: 1.5932x; 1.5932x over previous
//
#include <hip/hip_runtime.h>
#include <cstdint>
#include <cstddef>

#define NF 128
#define NH 64

typedef unsigned int uint32;
typedef int int4v __attribute__((ext_vector_type(4)));

// bf16 helpers (RNE pack, cheap unpack)
__device__ inline unsigned short f2bf(float f) {
  unsigned int u = __float_as_uint(f);
  return (unsigned short)((u + 0x7FFF + ((u >> 16) & 1)) >> 16);
}
__device__ inline float bf2f_lo(uint32 u) { return __uint_as_float(u << 16); }
__device__ inline float bf2f_hi(uint32 u) { return __uint_as_float(u & 0xFFFF0000u); }

// ---------------- build kernels ----------------

// Fused: blocks [0,G1) do gemm1 (H = x @ W1, bf16-packed out);
// blocks [G1,..) do dst-windowed degree count (pass = local&7 -> XCD-pinned).
// G1 is a multiple of 8 so count blocks keep blockIdx%8 == local%8.
__global__ __launch_bounds__(256, 4) void gemm1_count_kernel(
    const float* __restrict__ X, const float* __restrict__ W,
    uint32* __restrict__ Hb, int N,
    const int* __restrict__ ei, int E, int* __restrict__ cnt, int RW, int G1) {
  __shared__ float XsT[64][68];
  __shared__ float Ws[64 * 64];

  if ((int)blockIdx.x >= G1) {
    // ---- count part ----
    int b = blockIdx.x - G1;
    int pass = b & 7;
    int i = (b >> 3) * 256 + threadIdx.x;
    if (i * 4 >= E) return;
    int4v d = __builtin_nontemporal_load(((const int4v*)(ei + E)) + i);
    int lo = pass * RW, hi = lo + RW;
    if (d.x >= lo && d.x < hi) atomicAdd(&cnt[d.x], 1);
    if (d.y >= lo && d.y < hi) atomicAdd(&cnt[d.y], 1);
    if (d.z >= lo && d.z < hi) atomicAdd(&cnt[d.z], 1);
    if (d.w >= lo && d.w < hi) atomicAdd(&cnt[d.w], 1);
    return;
  }

  // ---- gemm1 part ----
  const int tid = threadIdx.x;
  const int n0 = blockIdx.x * 64;
  if (n0 >= N) return;
  const int tn = (tid >> 4) * 4;
  const int tf = (tid & 15) * 4;
  const int K = 128;

  float acc[4][4];
#pragma unroll
  for (int i = 0; i < 4; ++i)
#pragma unroll
    for (int j = 0; j < 4; ++j) acc[i][j] = 0.f;

  for (int kt = 0; kt < K / 64; ++kt) {
    {
      const float4* Wg = (const float4*)(W + (size_t)kt * 64 * 64);
      float4* Wl = (float4*)Ws;
#pragma unroll
      for (int j = 0; j < 4; ++j) Wl[tid + j * 256] = Wg[tid + j * 256];
    }
#pragma unroll
    for (int j = 0; j < 4; ++j) {
      int idx = tid + j * 256;
      int n = idx >> 4;
      int kq = idx & 15;
      float4 v = make_float4(0.f, 0.f, 0.f, 0.f);
      if (n0 + n < N)
        v = *(const float4*)(X + (size_t)(n0 + n) * K + kt * 64 + kq * 4);
      XsT[kq * 4 + 0][n] = v.x;
      XsT[kq * 4 + 1][n] = v.y;
      XsT[kq * 4 + 2][n] = v.z;
      XsT[kq * 4 + 3][n] = v.w;
    }
    __syncthreads();
#pragma unroll 8
    for (int k = 0; k < 64; ++k) {
      float4 xv = *(const float4*)(&XsT[k][tn]);
      float4 wv = *(const float4*)(&Ws[k * 64 + tf]);
      acc[0][0] = fmaf(xv.x, wv.x, acc[0][0]);
      acc[0][1] = fmaf(xv.x, wv.y, acc[0][1]);
      acc[0][2] = fmaf(xv.x, wv.z, acc[0][2]);
      acc[0][3] = fmaf(xv.x, wv.w, acc[0][3]);
      acc[1][0] = fmaf(xv.y, wv.x, acc[1][0]);
      acc[1][1] = fmaf(xv.y, wv.y, acc[1][1]);
      acc[1][2] = fmaf(xv.y, wv.z, acc[1][2]);
      acc[1][3] = fmaf(xv.y, wv.w, acc[1][3]);
      acc[2][0] = fmaf(xv.z, wv.x, acc[2][0]);
      acc[2][1] = fmaf(xv.z, wv.y, acc[2][1]);
      acc[2][2] = fmaf(xv.z, wv.z, acc[2][2]);
      acc[2][3] = fmaf(xv.z, wv.w, acc[2][3]);
      acc[3][0] = fmaf(xv.w, wv.x, acc[3][0]);
      acc[3][1] = fmaf(xv.w, wv.y, acc[3][1]);
      acc[3][2] = fmaf(xv.w, wv.z, acc[3][2]);
      acc[3][3] = fmaf(xv.w, wv.w, acc[3][3]);
    }
    __syncthreads();
  }
#pragma unroll
  for (int i = 0; i < 4; ++i) {
    int n = n0 + tn + i;
    if (n < N) {
      uint32 p0 = (uint32)f2bf(acc[i][0]) | ((uint32)f2bf(acc[i][1]) << 16);
      uint32 p1 = (uint32)f2bf(acc[i][2]) | ((uint32)f2bf(acc[i][3]) << 16);
      *(uint2*)(Hb + (size_t)n * 32 + tf / 2) = make_uint2(p0, p1);
    }
  }
}

// per-1024-element block sums
__global__ __launch_bounds__(256) void partial_kernel(const int* __restrict__ cnt, int N,
                                                      int* __restrict__ part) {
  __shared__ int sd[256];
  int t = threadIdx.x;
  int idx = blockIdx.x * 1024 + t * 4;
  int s = 0;
#pragma unroll
  for (int j = 0; j < 4; ++j)
    if (idx + j < N) s += cnt[idx + j];
  sd[t] = s;
  __syncthreads();
  for (int off = 128; off > 0; off >>= 1) {
    if (t < off) sd[t] += sd[t + off];
    __syncthreads();
  }
  if (t == 0) part[blockIdx.x] = sd[0];
}

// exclusive-scan the block partials (NB <= 128), write total to rowptr[N]
__global__ __launch_bounds__(128) void scanp_kernel(int* __restrict__ part, int NB,
                                                    int* __restrict__ rowptrN) {
  __shared__ int s[128];
  int t = threadIdx.x;
  int v = (t < NB) ? part[t] : 0;
  s[t] = v;
  __syncthreads();
  for (int off = 1; off < 128; off <<= 1) {
    int add = (t >= off) ? s[t - off] : 0;
    __syncthreads();
    s[t] += add;
    __syncthreads();
  }
  if (t < NB) part[t] = s[t] - v;  // exclusive
  if (t == 0) rowptrN[0] = s[127];
}

// rowptr (exclusive scan of cnt) + cnt2 (running cursor copy) + dinv
__global__ __launch_bounds__(256) void rowptr_kernel(const int* __restrict__ cnt,
                                                     const int* __restrict__ part,
                                                     int* __restrict__ rowptr,
                                                     int* __restrict__ cnt2,
                                                     float* __restrict__ dinv, int N) {
  __shared__ int s[256];
  int t = threadIdx.x;
  int idx = blockIdx.x * 1024 + t * 4;
  int c[4];
  int ts = 0;
#pragma unroll
  for (int j = 0; j < 4; ++j) {
    c[j] = (idx + j < N) ? cnt[idx + j] : 0;
    ts += c[j];
  }
  s[t] = ts;
  __syncthreads();
  for (int off = 1; off < 256; off <<= 1) {
    int add = (t >= off) ? s[t - off] : 0;
    __syncthreads();
    s[t] += add;
    __syncthreads();
  }
  int run = s[t] - ts + part[blockIdx.x];
#pragma unroll
  for (int j = 0; j < 4; ++j) {
    if (idx + j < N) {
      rowptr[idx + j] = run;
      cnt2[idx + j] = run;
      dinv[idx + j] = rsqrtf((float)(c[j] + 1));
    }
    run += c[j];
  }
}

// dst-windowed CSR scatter (src, weight), pass = blockIdx%8 -> one XCD per
// col2 window so lines assemble in that XCD's L2 before writeback.
__global__ __launch_bounds__(256) void fill_kernel(const int* __restrict__ ei, int E,
                                                   int* __restrict__ cnt2,
                                                   const float* __restrict__ dinv,
                                                   int2* __restrict__ col2, int RW) {
  int pass = blockIdx.x & 7;
  int i = (blockIdx.x >> 3) * 256 + threadIdx.x;
  if (i * 4 >= E) return;
  int4v sv = __builtin_nontemporal_load(((const int4v*)ei) + i);
  int4v dv = __builtin_nontemporal_load(((const int4v*)(ei + E)) + i);
  int lo = pass * RW, hi = lo + RW;
  int ss[4] = {sv.x, sv.y, sv.z, sv.w};
  int dd[4] = {dv.x, dv.y, dv.z, dv.w};
#pragma unroll
  for (int j = 0; j < 4; ++j) {
    int d = dd[j];
    if (d < lo || d >= hi) continue;
    int s = ss[j];
    float w = dinv[s] * dinv[d];
    int pos = atomicAdd(&cnt2[d], 1);
    col2[pos] = make_int2(s, __float_as_int(w));
  }
}

// ---------------- prop kernel ----------------

// Fused CSR aggregate + bias + relu + next-layer 64x64 linear.
// Wave = 1 node. 4 edge-quarters x 16 lanes; each lane holds a feature QUAD
// (uint2 = 4 bf16) -> one gather instruction covers 4 edges (8 cache lines).
// col2 read nontemporal so the edge stream doesn't evict H from L2.
// FINAL=1: 64->2 linear + log_softmax instead of the 64x64 transform.
template <int FINAL>
__global__ __launch_bounds__(256) void prop_fused_kernel(
    const uint32* __restrict__ H32, const int* __restrict__ rowptr,
    const int2* __restrict__ col2, const float* __restrict__ dinv,
    const float* __restrict__ bias, const float* __restrict__ Wn,
    const float* __restrict__ blin, void* __restrict__ outv, int N) {
  __shared__ float Ws[FINAL ? 4 : 64 * 64];
  __shared__ float rbuf[FINAL ? 1 : 4][64];
  const int lane = threadIdx.x & 63;
  const int widx = threadIdx.x >> 6;
  const int fq = lane & 15;   // feature quad: feats 4fq..4fq+3
  const int qtr = lane >> 4;  // edge quarter 0..3

  if (!FINAL) {
    const float4* Wg = (const float4*)Wn;
    float4* Wl = (float4*)Ws;
    for (int i = threadIdx.x; i < 1024; i += 256) Wl[i] = Wg[i];
    __syncthreads();
  }

  int n = blockIdx.x * 4 + widx;
  n = __builtin_amdgcn_readfirstlane(n);
  if (n >= N) return;

  const int e0 = rowptr[n];
  const int m = rowptr[n + 1] - e0;
  const unsigned long long* ecs = (const unsigned long long*)(col2 + e0);

  float acc0 = 0.f, acc1 = 0.f, acc2 = 0.f, acc3 = 0.f;
  const int nq = (m + 3) >> 2;
  for (int it = 0; it < nq; ++it) {
    int er = it * 4 + qtr;
    bool v = er < m;
    unsigned long long c = __builtin_nontemporal_load(ecs + (v ? er : 0));
    int src = (int)(c & 0xFFFFFFFFull);
    float w = v ? __uint_as_float((uint32)(c >> 32)) : 0.f;
    uint2 u = *(const uint2*)(H32 + (size_t)src * 32 + fq * 2);
    acc0 = fmaf(w, bf2f_lo(u.x), acc0);
    acc1 = fmaf(w, bf2f_hi(u.x), acc1);
    acc2 = fmaf(w, bf2f_lo(u.y), acc2);
    acc3 = fmaf(w, bf2f_hi(u.y), acc3);
  }
  // reduce the 4 edge-quarters (lanes l, l+16, l+32, l+48)
  acc0 += __shfl_xor(acc0, 16, 64);
  acc1 += __shfl_xor(acc1, 16, 64);
  acc2 += __shfl_xor(acc2, 16, 64);
  acc3 += __shfl_xor(acc3, 16, 64);
  acc0 += __shfl_xor(acc0, 32, 64);
  acc1 += __shfl_xor(acc1, 32, 64);
  acc2 += __shfl_xor(acc2, 32, 64);
  acc3 += __shfl_xor(acc3, 32, 64);

  // self loop (all lanes; broadcast-ish L2 hit)
  float di = dinv[n];
  float d2 = di * di;
  uint2 su = *(const uint2*)(H32 + (size_t)n * 32 + fq * 2);
  acc0 = fmaf(d2, bf2f_lo(su.x), acc0);
  acc1 = fmaf(d2, bf2f_hi(su.x), acc1);
  acc2 = fmaf(d2, bf2f_lo(su.y), acc2);
  acc3 = fmaf(d2, bf2f_hi(su.y), acc3);

  float4 bv = *(const float4*)(bias + fq * 4);
  float r0 = acc0 + bv.x;
  float r1 = acc1 + bv.y;
  float r2 = acc2 + bv.z;
  float r3 = acc3 + bv.w;
  r0 = r0 > 0.f ? r0 : 0.f;
  r1 = r1 > 0.f ? r1 : 0.f;
  r2 = r2 > 0.f ? r2 : 0.f;
  r3 = r3 > 0.f ? r3 : 0.f;

  if (FINAL) {
    float t0 = 0.f, t1 = 0.f;
    if (qtr == 0) {
      float4 wa = ((const float4*)Wn)[2 * fq];      // feats 4fq,4fq+1 x {c0,c1}
      float4 wb = ((const float4*)Wn)[2 * fq + 1];  // feats 4fq+2,4fq+3
      t0 = r0 * wa.x + r1 * wa.z + r2 * wb.x + r3 * wb.z;
      t1 = r0 * wa.y + r1 * wa.w + r2 * wb.y + r3 * wb.w;
    }
#pragma unroll
    for (int off = 32; off > 0; off >>= 1) {
      t0 += __shfl_xor(t0, off, 64);
      t1 += __shfl_xor(t1, off, 64);
    }
    if (lane == 0) {
      float* out = (float*)outv;
      float l0 = t0 + blin[0];
      float l1 = t1 + blin[1];
      float mx = fmaxf(l0, l1);
      float lz = mx + logf(expf(l0 - mx) + expf(l1 - mx));
      out[(size_t)n * 2 + 0] = l0 - lz;
      out[(size_t)n * 2 + 1] = l1 - lz;
    }
  } else {
    if (qtr == 0) *(float4*)(&rbuf[widx][4 * fq]) = make_float4(r0, r1, r2, r3);
    __builtin_amdgcn_wave_barrier();  // ordering only; compiler inserts waits
    float o = 0.f;
#pragma unroll
    for (int q = 0; q < 16; ++q) {
      float4 rv = *(const float4*)(&rbuf[widx][4 * q]);
      o = fmaf(rv.x, Ws[(4 * q + 0) * 64 + lane], o);
      o = fmaf(rv.y, Ws[(4 * q + 1) * 64 + lane], o);
      o = fmaf(rv.z, Ws[(4 * q + 2) * 64 + lane], o);
      o = fmaf(rv.w, Ws[(4 * q + 3) * 64 + lane], o);
    }
    ((unsigned short*)outv)[(size_t)n * 64 + lane] = f2bf(o);
  }
}

// ---------------- launcher ----------------

extern "C" void kernel_launch(void* const* d_in, const int* in_sizes, int n_in,
                              void* d_out, int out_size, void* d_ws, size_t ws_size,
                              hipStream_t stream) {
  const float* x  = (const float*)d_in[0];
  const int*   ei = (const int*)d_in[1];
  const float* W1 = (const float*)d_in[2];
  const float* b1 = (const float*)d_in[3];
  const float* W2 = (const float*)d_in[4];
  const float* b2 = (const float*)d_in[5];
  const float* W3 = (const float*)d_in[6];
  const float* b3 = (const float*)d_in[7];
  const float* Wl = (const float*)d_in[8];
  const float* bl = (const float*)d_in[9];
  float* out = (float*)d_out;

  const int N = in_sizes[0] / NF;  // 100000
  const int E = in_sizes[1] / 2;   // 1600000

  char* w = (char*)d_ws;
  size_t off = 0;
  auto alloc = [&](size_t bytes) {
    void* p = w + off;
    off += bytes;
    off = (off + 15) & ~(size_t)15;
    return p;
  };
  int*    cnt    = (int*)alloc((size_t)N * 4);
  int*    cnt2   = (int*)alloc((size_t)N * 4);
  int*    rowptr = (int*)alloc((size_t)(N + 1) * 4);
  int*    part   = (int*)alloc(256 * 4);
  float*  dinv   = (float*)alloc((size_t)N * 4);
  int2*   col2   = (int2*)alloc((size_t)E * 8);
  uint32* hA     = (uint32*)alloc((size_t)N * 32 * 4);  // bf16 x2 packed rows
  uint32* hB     = (uint32*)alloc((size_t)N * 32 * 4);

  const int NB = (N + 1023) / 1024;        // 98 (<=128 required by scanp)
  const int RW = (N + 7) / 8;              // 12500-node dst window per XCD
  const int NCHUNK = (E / 4 + 255) / 256;  // edge-quad chunks
  const int G1 = ((((N + 63) / 64) + 7) / 8) * 8;  // gemm blocks, multiple of 8

  hipMemsetAsync(cnt, 0, (size_t)N * 4, stream);
  hipLaunchKernelGGL(gemm1_count_kernel, dim3(G1 + 8 * NCHUNK), dim3(256), 0, stream,
                     x, W1, hA, N, ei, E, cnt, RW, G1);
  hipLaunchKernelGGL(partial_kernel, dim3(NB), dim3(256), 0, stream, cnt, N, part);
  hipLaunchKernelGGL(scanp_kernel, dim3(1), dim3(128), 0, stream, part, NB, rowptr + N);
  hipLaunchKernelGGL(rowptr_kernel, dim3(NB), dim3(256), 0, stream,
                     cnt, part, rowptr, cnt2, dinv, N);
  hipLaunchKernelGGL(fill_kernel, dim3(8 * NCHUNK), dim3(256), 0, stream,
                     ei, E, cnt2, dinv, col2, RW);

  hipLaunchKernelGGL(prop_fused_kernel<0>, dim3((N + 3) / 4), dim3(256), 0, stream,
                     hA, rowptr, col2, dinv, b1, W2, (const float*)nullptr, (void*)hB, N);
  hipLaunchKernelGGL(prop_fused_kernel<0>, dim3((N + 3) / 4), dim3(256), 0, stream,
                     hB, rowptr, col2, dinv, b2, W3, (const float*)nullptr, (void*)hA, N);
  hipLaunchKernelGGL(prop_fused_kernel<1>, dim3((N + 3) / 4), dim3(256), 0, stream,
                     hA, rowptr, col2, dinv, b3, Wl, bl, (void*)out, N);
}

// Round 10
// 470.326 us; speedup vs baseline: 1.6138x; 1.0129x over previous
//
#include <hip/hip_runtime.h>
#include <cstdint>
#include <cstddef>

#define NF 128
#define NH 64

typedef unsigned int uint32;

// bf16 helpers (RNE pack, cheap unpack)
__device__ inline unsigned short f2bf(float f) {
  unsigned int u = __float_as_uint(f);
  return (unsigned short)((u + 0x7FFF + ((u >> 16) & 1)) >> 16);
}
__device__ inline float bf2f_lo(uint32 u) { return __uint_as_float(u << 16); }
__device__ inline float bf2f_hi(uint32 u) { return __uint_as_float(u & 0xFFFF0000u); }

// ---------------- build kernels ----------------

// Fused: blocks [0,G1) do gemm1 (H = x @ W1, bf16-packed out);
// blocks [G1,..) do dst-windowed degree count (pass = local&7 -> XCD-pinned).
__global__ __launch_bounds__(256, 4) void gemm1_count_kernel(
    const float* __restrict__ X, const float* __restrict__ W,
    uint32* __restrict__ Hb, int N,
    const int* __restrict__ ei, int E, int* __restrict__ cnt, int RW, int G1) {
  __shared__ float XsT[64][68];
  __shared__ float Ws[64 * 64];

  if ((int)blockIdx.x >= G1) {
    // ---- count part ----
    int b = blockIdx.x - G1;
    int pass = b & 7;
    int i = (b >> 3) * 256 + threadIdx.x;
    if (i * 4 >= E) return;
    int4 d = ((const int4*)(ei + E))[i];
    int lo = pass * RW, hi = lo + RW;
    if (d.x >= lo && d.x < hi) atomicAdd(&cnt[d.x], 1);
    if (d.y >= lo && d.y < hi) atomicAdd(&cnt[d.y], 1);
    if (d.z >= lo && d.z < hi) atomicAdd(&cnt[d.z], 1);
    if (d.w >= lo && d.w < hi) atomicAdd(&cnt[d.w], 1);
    return;
  }

  // ---- gemm1 part ----
  const int tid = threadIdx.x;
  const int n0 = blockIdx.x * 64;
  if (n0 >= N) return;
  const int tn = (tid >> 4) * 4;
  const int tf = (tid & 15) * 4;
  const int K = 128;

  float acc[4][4];
#pragma unroll
  for (int i = 0; i < 4; ++i)
#pragma unroll
    for (int j = 0; j < 4; ++j) acc[i][j] = 0.f;

  for (int kt = 0; kt < K / 64; ++kt) {
    {
      const float4* Wg = (const float4*)(W + (size_t)kt * 64 * 64);
      float4* Wl = (float4*)Ws;
#pragma unroll
      for (int j = 0; j < 4; ++j) Wl[tid + j * 256] = Wg[tid + j * 256];
    }
#pragma unroll
    for (int j = 0; j < 4; ++j) {
      int idx = tid + j * 256;
      int n = idx >> 4;
      int kq = idx & 15;
      float4 v = make_float4(0.f, 0.f, 0.f, 0.f);
      if (n0 + n < N)
        v = *(const float4*)(X + (size_t)(n0 + n) * K + kt * 64 + kq * 4);
      XsT[kq * 4 + 0][n] = v.x;
      XsT[kq * 4 + 1][n] = v.y;
      XsT[kq * 4 + 2][n] = v.z;
      XsT[kq * 4 + 3][n] = v.w;
    }
    __syncthreads();
#pragma unroll 8
    for (int k = 0; k < 64; ++k) {
      float4 xv = *(const float4*)(&XsT[k][tn]);
      float4 wv = *(const float4*)(&Ws[k * 64 + tf]);
      acc[0][0] = fmaf(xv.x, wv.x, acc[0][0]);
      acc[0][1] = fmaf(xv.x, wv.y, acc[0][1]);
      acc[0][2] = fmaf(xv.x, wv.z, acc[0][2]);
      acc[0][3] = fmaf(xv.x, wv.w, acc[0][3]);
      acc[1][0] = fmaf(xv.y, wv.x, acc[1][0]);
      acc[1][1] = fmaf(xv.y, wv.y, acc[1][1]);
      acc[1][2] = fmaf(xv.y, wv.z, acc[1][2]);
      acc[1][3] = fmaf(xv.y, wv.w, acc[1][3]);
      acc[2][0] = fmaf(xv.z, wv.x, acc[2][0]);
      acc[2][1] = fmaf(xv.z, wv.y, acc[2][1]);
      acc[2][2] = fmaf(xv.z, wv.z, acc[2][2]);
      acc[2][3] = fmaf(xv.z, wv.w, acc[2][3]);
      acc[3][0] = fmaf(xv.w, wv.x, acc[3][0]);
      acc[3][1] = fmaf(xv.w, wv.y, acc[3][1]);
      acc[3][2] = fmaf(xv.w, wv.z, acc[3][2]);
      acc[3][3] = fmaf(xv.w, wv.w, acc[3][3]);
    }
    __syncthreads();
  }
#pragma unroll
  for (int i = 0; i < 4; ++i) {
    int n = n0 + tn + i;
    if (n < N) {
      uint32 p0 = (uint32)f2bf(acc[i][0]) | ((uint32)f2bf(acc[i][1]) << 16);
      uint32 p1 = (uint32)f2bf(acc[i][2]) | ((uint32)f2bf(acc[i][3]) << 16);
      *(uint2*)(Hb + (size_t)n * 32 + tf / 2) = make_uint2(p0, p1);
    }
  }
}

// per-1024-element block sums
__global__ __launch_bounds__(256) void partial_kernel(const int* __restrict__ cnt, int N,
                                                      int* __restrict__ part) {
  __shared__ int sd[256];
  int t = threadIdx.x;
  int idx = blockIdx.x * 1024 + t * 4;
  int s = 0;
#pragma unroll
  for (int j = 0; j < 4; ++j)
    if (idx + j < N) s += cnt[idx + j];
  sd[t] = s;
  __syncthreads();
  for (int off = 128; off > 0; off >>= 1) {
    if (t < off) sd[t] += sd[t + off];
    __syncthreads();
  }
  if (t == 0) part[blockIdx.x] = sd[0];
}

// exclusive-scan the block partials (NB <= 128), write total to rowptr[N]
__global__ __launch_bounds__(128) void scanp_kernel(int* __restrict__ part, int NB,
                                                    int* __restrict__ rowptrN) {
  __shared__ int s[128];
  int t = threadIdx.x;
  int v = (t < NB) ? part[t] : 0;
  s[t] = v;
  __syncthreads();
  for (int off = 1; off < 128; off <<= 1) {
    int add = (t >= off) ? s[t - off] : 0;
    __syncthreads();
    s[t] += add;
    __syncthreads();
  }
  if (t < NB) part[t] = s[t] - v;  // exclusive
  if (t == 0) rowptrN[0] = s[127];
}

// rowptr (exclusive scan of cnt) + cnt2 (running cursor copy) + dinv
__global__ __launch_bounds__(256) void rowptr_kernel(const int* __restrict__ cnt,
                                                     const int* __restrict__ part,
                                                     int* __restrict__ rowptr,
                                                     int* __restrict__ cnt2,
                                                     float* __restrict__ dinv, int N) {
  __shared__ int s[256];
  int t = threadIdx.x;
  int idx = blockIdx.x * 1024 + t * 4;
  int c[4];
  int ts = 0;
#pragma unroll
  for (int j = 0; j < 4; ++j) {
    c[j] = (idx + j < N) ? cnt[idx + j] : 0;
    ts += c[j];
  }
  s[t] = ts;
  __syncthreads();
  for (int off = 1; off < 256; off <<= 1) {
    int add = (t >= off) ? s[t - off] : 0;
    __syncthreads();
    s[t] += add;
    __syncthreads();
  }
  int run = s[t] - ts + part[blockIdx.x];
#pragma unroll
  for (int j = 0; j < 4; ++j) {
    if (idx + j < N) {
      rowptr[idx + j] = run;
      cnt2[idx + j] = run;
      dinv[idx + j] = rsqrtf((float)(c[j] + 1));
    }
    run += c[j];
  }
}

// dst-windowed CSR scatter (src, weight), pass = blockIdx%8 -> one XCD per
// col2 window so lines assemble in that XCD's L2 before writeback.
__global__ __launch_bounds__(256) void fill_kernel(const int* __restrict__ ei, int E,
                                                   int* __restrict__ cnt2,
                                                   const float* __restrict__ dinv,
                                                   int2* __restrict__ col2, int RW) {
  int pass = blockIdx.x & 7;
  int i = (blockIdx.x >> 3) * 256 + threadIdx.x;
  if (i * 4 >= E) return;
  int4 sv = ((const int4*)ei)[i];
  int4 dv = ((const int4*)(ei + E))[i];
  int lo = pass * RW, hi = lo + RW;
  int ss[4] = {sv.x, sv.y, sv.z, sv.w};
  int dd[4] = {dv.x, dv.y, dv.z, dv.w};
#pragma unroll
  for (int j = 0; j < 4; ++j) {
    int d = dd[j];
    if (d < lo || d >= hi) continue;
    int s = ss[j];
    float w = dinv[s] * dinv[d];
    int pos = atomicAdd(&cnt2[d], 1);
    col2[pos] = make_int2(s, __float_as_int(w));
  }
}

// ---------------- prop kernel ----------------

// Fused CSR aggregate over bf16 H (wave = node; lane = feature-PAIR; two
// 32-lane halves process even/odd edges -> 2 edges per gather instruction)
// + bias + relu + next-layer 64x64 linear via wave-local LDS exchange.
// NT=1: gather H rows with nontemporal loads (bypass L2 allocate; serve from
// L3) -- A/B experiment for the L2-fill-port bottleneck theory.
// FINAL=1: 64->2 linear + log_softmax instead.
template <int FINAL, int NT>
__global__ __launch_bounds__(256) void prop_fused_kernel(
    const uint32* __restrict__ H32, const int* __restrict__ rowptr,
    const int2* __restrict__ col2, const float* __restrict__ dinv,
    const float* __restrict__ bias, const float* __restrict__ Wn,
    const float* __restrict__ blin, void* __restrict__ outv, int N) {
  __shared__ float Ws[FINAL ? 4 : 64 * 64];
  __shared__ float rbuf[FINAL ? 1 : 4][64];
  const int lane = threadIdx.x & 63;
  const int widx = threadIdx.x >> 6;
  const int fl = lane & 31;   // feature-pair index (features 2fl, 2fl+1)
  const int half = lane >> 5; // 0: even edges, 1: odd edges

  if (!FINAL) {
    const float4* Wg = (const float4*)Wn;
    float4* Wl = (float4*)Ws;
    for (int i = threadIdx.x; i < 1024; i += 256) Wl[i] = Wg[i];
    __syncthreads();
  }

  int n = blockIdx.x * 4 + widx;
  n = __builtin_amdgcn_readfirstlane(n);
  if (n >= N) return;

  int e0 = rowptr[n];
  int e1 = rowptr[n + 1];
  float di = dinv[n];
  const int2* ec = col2 + e0;
  const int m = e1 - e0;

  float acc0 = 0.f, acc1 = 0.f;
  if (half == 0) {  // self-loop counted once
    uint32 u = H32[(size_t)n * 32 + fl];
    float w = di * di;
    acc0 = bf2f_lo(u) * w;
    acc1 = bf2f_hi(u) * w;
  }

#define GATHER(dst, srcidx)                                          \
  {                                                                  \
    const uint32* p_ = H32 + (size_t)(srcidx) * 32 + fl;             \
    dst = NT ? __builtin_nontemporal_load(p_) : *p_;                 \
  }

  const int npair = m >> 1;
  const int nfull = npair >> 3;
  for (int b = 0; b < nfull; ++b) {
    int s[8];
    float wv[8];
#pragma unroll
    for (int j = 0; j < 8; ++j) {
      int2 c = ec[2 * (b * 8 + j) + half];
      s[j] = c.x;
      wv[j] = __int_as_float(c.y);
    }
    uint32 u[8];
#pragma unroll
    for (int j = 0; j < 8; ++j) GATHER(u[j], s[j]);
#pragma unroll
    for (int j = 0; j < 8; ++j) {
      acc0 = fmaf(wv[j], bf2f_lo(u[j]), acc0);
      acc1 = fmaf(wv[j], bf2f_hi(u[j]), acc1);
    }
  }
  for (int t = nfull * 8; t < npair; ++t) {
    int2 c = ec[2 * t + half];
    uint32 u;
    GATHER(u, c.x);
    float w = __int_as_float(c.y);
    acc0 = fmaf(w, bf2f_lo(u), acc0);
    acc1 = fmaf(w, bf2f_hi(u), acc1);
  }
  if ((m & 1) && half == 0) {  // odd tail edge
    int2 c = ec[m - 1];
    uint32 u;
    GATHER(u, c.x);
    float w = __int_as_float(c.y);
    acc0 = fmaf(w, bf2f_lo(u), acc0);
    acc1 = fmaf(w, bf2f_hi(u), acc1);
  }
#undef GATHER
  // combine even/odd halves (lane ^ 32 holds the other partial)
  acc0 += __shfl_xor(acc0, 32, 64);
  acc1 += __shfl_xor(acc1, 32, 64);

  float2 bv = ((const float2*)bias)[fl];
  float r0 = acc0 + bv.x;
  float r1 = acc1 + bv.y;
  r0 = r0 > 0.f ? r0 : 0.f;
  r1 = r1 > 0.f ? r1 : 0.f;

  if (FINAL) {
    float t0 = 0.f, t1 = 0.f;
    if (half == 0) {
      t0 = r0 * Wn[4 * fl + 0] + r1 * Wn[4 * fl + 2];
      t1 = r0 * Wn[4 * fl + 1] + r1 * Wn[4 * fl + 3];
    }
#pragma unroll
    for (int off = 32; off > 0; off >>= 1) {
      t0 += __shfl_xor(t0, off, 64);
      t1 += __shfl_xor(t1, off, 64);
    }
    if (lane == 0) {
      float* out = (float*)outv;
      float l0 = t0 + blin[0];
      float l1 = t1 + blin[1];
      float mx = fmaxf(l0, l1);
      float lz = mx + logf(expf(l0 - mx) + expf(l1 - mx));
      out[(size_t)n * 2 + 0] = l0 - lz;
      out[(size_t)n * 2 + 1] = l1 - lz;
    }
  } else {
    if (half == 0) *(float2*)(&rbuf[widx][2 * fl]) = make_float2(r0, r1);
    __builtin_amdgcn_wave_barrier();  // ordering only; compiler inserts waits
    float o = 0.f;
#pragma unroll
    for (int q = 0; q < 16; ++q) {
      float4 rv = *(const float4*)(&rbuf[widx][4 * q]);
      o = fmaf(rv.x, Ws[(4 * q + 0) * 64 + lane], o);
      o = fmaf(rv.y, Ws[(4 * q + 1) * 64 + lane], o);
      o = fmaf(rv.z, Ws[(4 * q + 2) * 64 + lane], o);
      o = fmaf(rv.w, Ws[(4 * q + 3) * 64 + lane], o);
    }
    ((unsigned short*)outv)[(size_t)n * 64 + lane] = f2bf(o);
  }
}

// ---------------- launcher ----------------

extern "C" void kernel_launch(void* const* d_in, const int* in_sizes, int n_in,
                              void* d_out, int out_size, void* d_ws, size_t ws_size,
                              hipStream_t stream) {
  const float* x  = (const float*)d_in[0];
  const int*   ei = (const int*)d_in[1];
  const float* W1 = (const float*)d_in[2];
  const float* b1 = (const float*)d_in[3];
  const float* W2 = (const float*)d_in[4];
  const float* b2 = (const float*)d_in[5];
  const float* W3 = (const float*)d_in[6];
  const float* b3 = (const float*)d_in[7];
  const float* Wl = (const float*)d_in[8];
  const float* bl = (const float*)d_in[9];
  float* out = (float*)d_out;

  const int N = in_sizes[0] / NF;  // 100000
  const int E = in_sizes[1] / 2;   // 1600000

  char* w = (char*)d_ws;
  size_t off = 0;
  auto alloc = [&](size_t bytes) {
    void* p = w + off;
    off += bytes;
    off = (off + 15) & ~(size_t)15;
    return p;
  };
  int*    cnt    = (int*)alloc((size_t)N * 4);
  int*    cnt2   = (int*)alloc((size_t)N * 4);
  int*    rowptr = (int*)alloc((size_t)(N + 1) * 4);
  int*    part   = (int*)alloc(256 * 4);
  float*  dinv   = (float*)alloc((size_t)N * 4);
  int2*   col2   = (int2*)alloc((size_t)E * 8);
  uint32* hA     = (uint32*)alloc((size_t)N * 32 * 4);  // bf16 x2 packed rows
  uint32* hB     = (uint32*)alloc((size_t)N * 32 * 4);

  const int NB = (N + 1023) / 1024;        // 98 (<=128 required by scanp)
  const int RW = (N + 7) / 8;              // 12500-node dst window per XCD
  const int NCHUNK = (E / 4 + 255) / 256;  // edge-quad chunks
  const int G1 = ((((N + 63) / 64) + 7) / 8) * 8;  // gemm blocks, multiple of 8

  hipMemsetAsync(cnt, 0, (size_t)N * 4, stream);
  hipLaunchKernelGGL(gemm1_count_kernel, dim3(G1 + 8 * NCHUNK), dim3(256), 0, stream,
                     x, W1, hA, N, ei, E, cnt, RW, G1);
  hipLaunchKernelGGL(partial_kernel, dim3(NB), dim3(256), 0, stream, cnt, N, part);
  hipLaunchKernelGGL(scanp_kernel, dim3(1), dim3(128), 0, stream, part, NB, rowptr + N);
  hipLaunchKernelGGL(rowptr_kernel, dim3(NB), dim3(256), 0, stream,
                     cnt, part, rowptr, cnt2, dinv, N);
  hipLaunchKernelGGL(fill_kernel, dim3(8 * NCHUNK), dim3(256), 0, stream,
                     ei, E, cnt2, dinv, col2, RW);

  // layer 1: normal gather; layer 2: NT gather (A/B experiment); layer 3: normal
  hipLaunchKernelGGL((prop_fused_kernel<0, 0>), dim3((N + 3) / 4), dim3(256), 0, stream,
                     hA, rowptr, col2, dinv, b1, W2, (const float*)nullptr, (void*)hB, N);
  hipLaunchKernelGGL((prop_fused_kernel<0, 1>), dim3((N + 3) / 4), dim3(256), 0, stream,
                     hB, rowptr, col2, dinv, b2, W3, (const float*)nullptr, (void*)hA, N);
  hipLaunchKernelGGL((prop_fused_kernel<1, 0>), dim3((N + 3) / 4), dim3(256), 0, stream,
                     hA, rowptr, col2, dinv, b3, Wl, bl, (void*)out, N);
}

// Round 11
// 428.718 us; speedup vs baseline: 1.7704x; 1.0971x over previous
//
#include <hip/hip_runtime.h>
#include <cstdint>
#include <cstddef>

#define NF 128
#define NH 64

typedef unsigned int uint32;
typedef short bf16x8 __attribute__((ext_vector_type(8)));
typedef float f32x4 __attribute__((ext_vector_type(4)));

// bf16 helpers (RNE pack, cheap unpack)
__device__ inline unsigned short f2bf(float f) {
  unsigned int u = __float_as_uint(f);
  return (unsigned short)((u + 0x7FFF + ((u >> 16) & 1)) >> 16);
}
__device__ inline float bf2f_lo(uint32 u) { return __uint_as_float(u << 16); }
__device__ inline float bf2f_hi(uint32 u) { return __uint_as_float(u & 0xFFFF0000u); }

// ---------------- build kernels ----------------

// dst-windowed count, P=4 windows: pass = blockIdx&3 (cnt window 100KB, L2-local)
__global__ __launch_bounds__(256) void count_kernel(const int* __restrict__ ei, int E,
                                                    int* __restrict__ cnt, int RW) {
  int pass = blockIdx.x & 3;
  int i = (blockIdx.x >> 2) * 256 + threadIdx.x;
  if (i * 4 >= E) return;
  int4 d = ((const int4*)(ei + E))[i];
  int lo = pass * RW, hi = lo + RW;
  if (d.x >= lo && d.x < hi) atomicAdd(&cnt[d.x], 1);
  if (d.y >= lo && d.y < hi) atomicAdd(&cnt[d.y], 1);
  if (d.z >= lo && d.z < hi) atomicAdd(&cnt[d.z], 1);
  if (d.w >= lo && d.w < hi) atomicAdd(&cnt[d.w], 1);
}

// per-1024-element block sums
__global__ __launch_bounds__(256) void partial_kernel(const int* __restrict__ cnt, int N,
                                                      int* __restrict__ part) {
  __shared__ int sd[256];
  int t = threadIdx.x;
  int idx = blockIdx.x * 1024 + t * 4;
  int s = 0;
#pragma unroll
  for (int j = 0; j < 4; ++j)
    if (idx + j < N) s += cnt[idx + j];
  sd[t] = s;
  __syncthreads();
  for (int off = 128; off > 0; off >>= 1) {
    if (t < off) sd[t] += sd[t + off];
    __syncthreads();
  }
  if (t == 0) part[blockIdx.x] = sd[0];
}

// exclusive-scan the block partials (NB <= 128), write total to rowptr[N]
__global__ __launch_bounds__(128) void scanp_kernel(int* __restrict__ part, int NB,
                                                    int* __restrict__ rowptrN) {
  __shared__ int s[128];
  int t = threadIdx.x;
  int v = (t < NB) ? part[t] : 0;
  s[t] = v;
  __syncthreads();
  for (int off = 1; off < 128; off <<= 1) {
    int add = (t >= off) ? s[t - off] : 0;
    __syncthreads();
    s[t] += add;
    __syncthreads();
  }
  if (t < NB) part[t] = s[t] - v;  // exclusive
  if (t == 0) rowptrN[0] = s[127];
}

// rowptr (exclusive scan of cnt) + cnt2 (running cursor copy) + dinv
__global__ __launch_bounds__(256) void rowptr_kernel(const int* __restrict__ cnt,
                                                     const int* __restrict__ part,
                                                     int* __restrict__ rowptr,
                                                     int* __restrict__ cnt2,
                                                     float* __restrict__ dinv, int N) {
  __shared__ int s[256];
  int t = threadIdx.x;
  int idx = blockIdx.x * 1024 + t * 4;
  int c[4];
  int ts = 0;
#pragma unroll
  for (int j = 0; j < 4; ++j) {
    c[j] = (idx + j < N) ? cnt[idx + j] : 0;
    ts += c[j];
  }
  s[t] = ts;
  __syncthreads();
  for (int off = 1; off < 256; off <<= 1) {
    int add = (t >= off) ? s[t - off] : 0;
    __syncthreads();
    s[t] += add;
    __syncthreads();
  }
  int run = s[t] - ts + part[blockIdx.x];
#pragma unroll
  for (int j = 0; j < 4; ++j) {
    if (idx + j < N) {
      rowptr[idx + j] = run;
      cnt2[idx + j] = run;
      dinv[idx + j] = rsqrtf((float)(c[j] + 1));
    }
    run += c[j];
  }
}

// dst-windowed CSR scatter (src, weight), P=4 windows: col2 window 3.2MB,
// assembles in L2 before writeback.
__global__ __launch_bounds__(256) void fill_kernel(const int* __restrict__ ei, int E,
                                                   int* __restrict__ cnt2,
                                                   const float* __restrict__ dinv,
                                                   int2* __restrict__ col2, int RW) {
  int pass = blockIdx.x & 3;
  int i = (blockIdx.x >> 2) * 256 + threadIdx.x;
  if (i * 4 >= E) return;
  int4 sv = ((const int4*)ei)[i];
  int4 dv = ((const int4*)(ei + E))[i];
  int lo = pass * RW, hi = lo + RW;
  int ss[4] = {sv.x, sv.y, sv.z, sv.w};
  int dd[4] = {dv.x, dv.y, dv.z, dv.w};
#pragma unroll
  for (int j = 0; j < 4; ++j) {
    int d = dd[j];
    if (d < lo || d >= hi) continue;
    int s = ss[j];
    float w = dinv[s] * dinv[d];
    int pos = atomicAdd(&cnt2[d], 1);
    col2[pos] = make_int2(s, __float_as_int(w));
  }
}

// ---------------- gemm1: MFMA bf16 ----------------

// H[n][64](bf16) = X[n][128](f32, cast bf16) @ W1[128][64](f32, cast bf16)
// Wave = 16 nodes; 4 n-tiles x 4 k-steps of mfma_f32_16x16x32_bf16.
// A frag: lane(m=l&15, g=l>>4) holds X[row=m][k=kk*32+g*8+i] (two float4 global
// loads, full 128B lines). B frag: same (g,i)->k map from L2-hot W (symmetric
// layout => any consistent k-bijection contracts correctly).
// C/D: col=lane&15, row=(lane>>4)*4+j (HW-verified mapping).
__global__ __launch_bounds__(256) void gemm1_mfma_kernel(
    const float* __restrict__ X, const float* __restrict__ W,
    uint32* __restrict__ Hb, int N) {
  const int lane = threadIdx.x & 63;
  const int wv = threadIdx.x >> 6;
  const int m = lane & 15;
  const int g = lane >> 4;
  const int base = blockIdx.x * 64 + wv * 16;
  int row = base + m;
  int rowc = row < N ? row : N - 1;
  const float* xp = X + (size_t)rowc * 128 + g * 8;

  f32x4 acc[4];
#pragma unroll
  for (int nt = 0; nt < 4; ++nt) acc[nt] = (f32x4){0.f, 0.f, 0.f, 0.f};

#pragma unroll
  for (int kk = 0; kk < 4; ++kk) {
    float4 alo = *(const float4*)(xp + kk * 32);
    float4 ahi = *(const float4*)(xp + kk * 32 + 4);
    bf16x8 a;
    a[0] = (short)f2bf(alo.x); a[1] = (short)f2bf(alo.y);
    a[2] = (short)f2bf(alo.z); a[3] = (short)f2bf(alo.w);
    a[4] = (short)f2bf(ahi.x); a[5] = (short)f2bf(ahi.y);
    a[6] = (short)f2bf(ahi.z); a[7] = (short)f2bf(ahi.w);
    const float* wp = W + (size_t)(kk * 32 + g * 8) * 64 + m;
#pragma unroll
    for (int nt = 0; nt < 4; ++nt) {
      bf16x8 b;
#pragma unroll
      for (int i = 0; i < 8; ++i)
        b[i] = (short)f2bf(wp[(size_t)i * 64 + nt * 16]);
      acc[nt] = __builtin_amdgcn_mfma_f32_16x16x32_bf16(a, b, acc[nt], 0, 0, 0);
    }
  }
  // write: node = base + g*4 + j, feat = nt*16 + m
  unsigned short* Hs = (unsigned short*)Hb;
#pragma unroll
  for (int j = 0; j < 4; ++j) {
    int n = base + g * 4 + j;
    if (n < N) {
#pragma unroll
      for (int nt = 0; nt < 4; ++nt)
        Hs[(size_t)n * 64 + nt * 16 + m] = f2bf(acc[nt][j]);
    }
  }
}

// ---------------- prop kernel (exact R6 winner) ----------------

// Fused CSR aggregate over bf16 H (wave = node; lane = feature-PAIR; two
// 32-lane halves process even/odd edges -> 2 edges per gather instruction)
// + bias + relu + next-layer 64x64 linear via wave-local LDS exchange.
// FINAL=1: 64->2 linear + log_softmax instead.
template <int FINAL>
__global__ __launch_bounds__(256) void prop_fused_kernel(
    const uint32* __restrict__ H32, const int* __restrict__ rowptr,
    const int2* __restrict__ col2, const float* __restrict__ dinv,
    const float* __restrict__ bias, const float* __restrict__ Wn,
    const float* __restrict__ blin, void* __restrict__ outv, int N) {
  __shared__ float Ws[FINAL ? 4 : 64 * 64];
  __shared__ float rbuf[FINAL ? 1 : 4][64];
  const int lane = threadIdx.x & 63;
  const int widx = threadIdx.x >> 6;
  const int fl = lane & 31;   // feature-pair index (features 2fl, 2fl+1)
  const int half = lane >> 5; // 0: even edges, 1: odd edges

  if (!FINAL) {
    const float4* Wg = (const float4*)Wn;
    float4* Wl = (float4*)Ws;
    for (int i = threadIdx.x; i < 1024; i += 256) Wl[i] = Wg[i];
    __syncthreads();
  }

  int n = blockIdx.x * 4 + widx;
  n = __builtin_amdgcn_readfirstlane(n);
  if (n >= N) return;

  int e0 = rowptr[n];
  int e1 = rowptr[n + 1];
  float di = dinv[n];
  const int2* ec = col2 + e0;
  const int m = e1 - e0;

  float acc0 = 0.f, acc1 = 0.f;
  if (half == 0) {  // self-loop counted once
    uint32 u = H32[(size_t)n * 32 + fl];
    float w = di * di;
    acc0 = bf2f_lo(u) * w;
    acc1 = bf2f_hi(u) * w;
  }

  const int npair = m >> 1;
  const int nfull = npair >> 3;
  for (int b = 0; b < nfull; ++b) {
    int s[8];
    float wv[8];
#pragma unroll
    for (int j = 0; j < 8; ++j) {
      int2 c = ec[2 * (b * 8 + j) + half];
      s[j] = c.x;
      wv[j] = __int_as_float(c.y);
    }
    uint32 u[8];
#pragma unroll
    for (int j = 0; j < 8; ++j) u[j] = H32[(size_t)s[j] * 32 + fl];
#pragma unroll
    for (int j = 0; j < 8; ++j) {
      acc0 = fmaf(wv[j], bf2f_lo(u[j]), acc0);
      acc1 = fmaf(wv[j], bf2f_hi(u[j]), acc1);
    }
  }
  for (int t = nfull * 8; t < npair; ++t) {
    int2 c = ec[2 * t + half];
    uint32 u = H32[(size_t)c.x * 32 + fl];
    float w = __int_as_float(c.y);
    acc0 = fmaf(w, bf2f_lo(u), acc0);
    acc1 = fmaf(w, bf2f_hi(u), acc1);
  }
  if ((m & 1) && half == 0) {  // odd tail edge
    int2 c = ec[m - 1];
    uint32 u = H32[(size_t)c.x * 32 + fl];
    float w = __int_as_float(c.y);
    acc0 = fmaf(w, bf2f_lo(u), acc0);
    acc1 = fmaf(w, bf2f_hi(u), acc1);
  }
  // combine even/odd halves (lane ^ 32 holds the other partial)
  acc0 += __shfl_xor(acc0, 32, 64);
  acc1 += __shfl_xor(acc1, 32, 64);

  float2 bv = ((const float2*)bias)[fl];
  float r0 = acc0 + bv.x;
  float r1 = acc1 + bv.y;
  r0 = r0 > 0.f ? r0 : 0.f;
  r1 = r1 > 0.f ? r1 : 0.f;

  if (FINAL) {
    float t0 = 0.f, t1 = 0.f;
    if (half == 0) {
      t0 = r0 * Wn[4 * fl + 0] + r1 * Wn[4 * fl + 2];
      t1 = r0 * Wn[4 * fl + 1] + r1 * Wn[4 * fl + 3];
    }
#pragma unroll
    for (int off = 32; off > 0; off >>= 1) {
      t0 += __shfl_xor(t0, off, 64);
      t1 += __shfl_xor(t1, off, 64);
    }
    if (lane == 0) {
      float* out = (float*)outv;
      float l0 = t0 + blin[0];
      float l1 = t1 + blin[1];
      float mx = fmaxf(l0, l1);
      float lz = mx + logf(expf(l0 - mx) + expf(l1 - mx));
      out[(size_t)n * 2 + 0] = l0 - lz;
      out[(size_t)n * 2 + 1] = l1 - lz;
    }
  } else {
    if (half == 0) *(float2*)(&rbuf[widx][2 * fl]) = make_float2(r0, r1);
    __builtin_amdgcn_wave_barrier();  // ordering only; compiler inserts waits
    float o = 0.f;
#pragma unroll
    for (int q = 0; q < 16; ++q) {
      float4 rv = *(const float4*)(&rbuf[widx][4 * q]);
      o = fmaf(rv.x, Ws[(4 * q + 0) * 64 + lane], o);
      o = fmaf(rv.y, Ws[(4 * q + 1) * 64 + lane], o);
      o = fmaf(rv.z, Ws[(4 * q + 2) * 64 + lane], o);
      o = fmaf(rv.w, Ws[(4 * q + 3) * 64 + lane], o);
    }
    ((unsigned short*)outv)[(size_t)n * 64 + lane] = f2bf(o);
  }
}

// ---------------- launcher ----------------

extern "C" void kernel_launch(void* const* d_in, const int* in_sizes, int n_in,
                              void* d_out, int out_size, void* d_ws, size_t ws_size,
                              hipStream_t stream) {
  const float* x  = (const float*)d_in[0];
  const int*   ei = (const int*)d_in[1];
  const float* W1 = (const float*)d_in[2];
  const float* b1 = (const float*)d_in[3];
  const float* W2 = (const float*)d_in[4];
  const float* b2 = (const float*)d_in[5];
  const float* W3 = (const float*)d_in[6];
  const float* b3 = (const float*)d_in[7];
  const float* Wl = (const float*)d_in[8];
  const float* bl = (const float*)d_in[9];
  float* out = (float*)d_out;

  const int N = in_sizes[0] / NF;  // 100000
  const int E = in_sizes[1] / 2;   // 1600000

  char* w = (char*)d_ws;
  size_t off = 0;
  auto alloc = [&](size_t bytes) {
    void* p = w + off;
    off += bytes;
    off = (off + 15) & ~(size_t)15;
    return p;
  };
  int*    cnt    = (int*)alloc((size_t)N * 4);
  int*    cnt2   = (int*)alloc((size_t)N * 4);
  int*    rowptr = (int*)alloc((size_t)(N + 1) * 4);
  int*    part   = (int*)alloc(256 * 4);
  float*  dinv   = (float*)alloc((size_t)N * 4);
  int2*   col2   = (int2*)alloc((size_t)E * 8);
  uint32* hA     = (uint32*)alloc((size_t)N * 32 * 4);  // bf16 x2 packed rows
  uint32* hB     = (uint32*)alloc((size_t)N * 32 * 4);

  const int NB = (N + 1023) / 1024;        // 98 (<=128 required by scanp)
  const int RW4 = (N + 3) / 4;             // 25000-node dst window (P=4)
  const int NCHUNK = (E / 4 + 255) / 256;  // edge-quad chunks

  hipMemsetAsync(cnt, 0, (size_t)N * 4, stream);
  hipLaunchKernelGGL(count_kernel, dim3(4 * NCHUNK), dim3(256), 0, stream,
                     ei, E, cnt, RW4);
  hipLaunchKernelGGL(partial_kernel, dim3(NB), dim3(256), 0, stream, cnt, N, part);
  hipLaunchKernelGGL(scanp_kernel, dim3(1), dim3(128), 0, stream, part, NB, rowptr + N);
  hipLaunchKernelGGL(rowptr_kernel, dim3(NB), dim3(256), 0, stream,
                     cnt, part, rowptr, cnt2, dinv, N);
  hipLaunchKernelGGL(fill_kernel, dim3(4 * NCHUNK), dim3(256), 0, stream,
                     ei, E, cnt2, dinv, col2, RW4);

  hipLaunchKernelGGL(gemm1_mfma_kernel, dim3((N + 63) / 64), dim3(256), 0, stream,
                     x, W1, hA, N);
  hipLaunchKernelGGL(prop_fused_kernel<0>, dim3((N + 3) / 4), dim3(256), 0, stream,
                     hA, rowptr, col2, dinv, b1, W2, (const float*)nullptr, (void*)hB, N);
  hipLaunchKernelGGL(prop_fused_kernel<0>, dim3((N + 3) / 4), dim3(256), 0, stream,
                     hB, rowptr, col2, dinv, b2, W3, (const float*)nullptr, (void*)hA, N);
  hipLaunchKernelGGL(prop_fused_kernel<1>, dim3((N + 3) / 4), dim3(256), 0, stream,
                     hA, rowptr, col2, dinv, b3, Wl, bl, (void*)out, N);
}